// Round 1
// baseline (241.675 us; speedup 1.0000x reference)
//
#include <hip/hip_runtime.h>

#define B_ 2
#define S_ 2048
#define E_ 256
#define H_ 32
#define DK_ 8

// ---------------------------------------------------------------------------
// Kernel 1: q[b][h][s][d] = cos(x[b][s][h*8+d] + theta[d])
// ---------------------------------------------------------------------------
__global__ __launch_bounds__(256) void qgen_kernel(
    const float* __restrict__ x, const float* __restrict__ theta,
    float* __restrict__ q) {
  int idx = blockIdx.x * 256 + threadIdx.x;   // over B*S*E = 1048576
  int e  = idx & (E_ - 1);
  int bs = idx >> 8;          // b*S + s
  int d  = e & (DK_ - 1);
  int h  = e >> 3;
  int b  = bs >> 11;          // S = 2048
  int s  = bs & (S_ - 1);
  float v = __cosf(x[idx] + theta[d]);
  q[(((size_t)(b * H_ + h) * S_) + s) * DK_ + d] = v;
}

// ---------------------------------------------------------------------------
// Kernel 2: per (b,h) attention. Block = 256 threads, handles 512 query rows.
// Full K-slab (2048x8 f32 = 64KB) + mask bias (8KB) in LDS.
// No-max softmax: |score| <= 8/sqrt(8) = 2.83, exp in [0.059, 17].
// Output written directly to [B][S][E] layout (e = h*8+d).
// ---------------------------------------------------------------------------
__global__ __launch_bounds__(256) void attn_kernel(
    const float* __restrict__ q, const int* __restrict__ mask,
    float* __restrict__ o) {
  __shared__ float4 Ks[S_ * 2];     // [k][0..1] as float4 pairs, 64KB
  __shared__ float  biasS[S_];      // 8KB, 0 or -1e9

  const int bh    = blockIdx.x >> 2;   // 0..63
  const int chunk = blockIdx.x & 3;    // 0..3
  const int b = bh >> 5;
  const int h = bh & 31;

  const float4* qv = (const float4*)(q + (size_t)bh * S_ * DK_);
  for (int i = threadIdx.x; i < S_ * 2; i += 256) Ks[i] = qv[i];
  const int* mb = mask + b * S_;
  for (int i = threadIdx.x; i < S_; i += 256)
    biasS[i] = (mb[i] != 0) ? 0.0f : -1e9f;
  __syncthreads();

  const int r0 = chunk * 512 + threadIdx.x;
  const int r1 = r0 + 256;

  float q0[8], q1[8];
  {
    float4 a = qv[2 * r0], c = qv[2 * r0 + 1];
    q0[0]=a.x; q0[1]=a.y; q0[2]=a.z; q0[3]=a.w;
    q0[4]=c.x; q0[5]=c.y; q0[6]=c.z; q0[7]=c.w;
    float4 a1 = qv[2 * r1], c1 = qv[2 * r1 + 1];
    q1[0]=a1.x; q1[1]=a1.y; q1[2]=a1.z; q1[3]=a1.w;
    q1[4]=c1.x; q1[5]=c1.y; q1[6]=c1.z; q1[7]=c1.w;
  }

  float num0[8] = {0,0,0,0,0,0,0,0};
  float num1[8] = {0,0,0,0,0,0,0,0};
  float den0 = 0.0f, den1 = 0.0f;
  const float scale = 0.35355339059327373f;  // 1/sqrt(8)

#pragma unroll 4
  for (int k = 0; k < S_; ++k) {
    float4 ka = Ks[2 * k], kb = Ks[2 * k + 1];
    float kr[8] = {ka.x, ka.y, ka.z, ka.w, kb.x, kb.y, kb.z, kb.w};
    float bias = biasS[k];
    float s0 = q0[0] * kr[0];
    float s1 = q1[0] * kr[0];
#pragma unroll
    for (int d = 1; d < 8; ++d) {
      s0 = fmaf(q0[d], kr[d], s0);
      s1 = fmaf(q1[d], kr[d], s1);
    }
    float e0 = __expf(fmaf(s0, scale, bias));
    float e1 = __expf(fmaf(s1, scale, bias));
    den0 += e0;
    den1 += e1;
#pragma unroll
    for (int d = 0; d < 8; ++d) {
      num0[d] = fmaf(e0, kr[d], num0[d]);
      num1[d] = fmaf(e1, kr[d], num1[d]);
    }
  }

  float inv0 = 1.0f / den0, inv1 = 1.0f / den1;
  float* o0 = o + (size_t)(b * S_ + r0) * E_ + h * DK_;
  float* o1 = o + (size_t)(b * S_ + r1) * E_ + h * DK_;
  ((float4*)o0)[0] = make_float4(num0[0]*inv0, num0[1]*inv0, num0[2]*inv0, num0[3]*inv0);
  ((float4*)o0)[1] = make_float4(num0[4]*inv0, num0[5]*inv0, num0[6]*inv0, num0[7]*inv0);
  ((float4*)o1)[0] = make_float4(num1[0]*inv0 + 0.0f, num1[1]*inv1, num1[2]*inv1, num1[3]*inv1);
  ((float4*)o1)[0] = make_float4(num1[0]*inv1, num1[1]*inv1, num1[2]*inv1, num1[3]*inv1);
  ((float4*)o1)[1] = make_float4(num1[4]*inv1, num1[5]*inv1, num1[6]*inv1, num1[7]*inv1);
}

// ---------------------------------------------------------------------------
// Kernel 3: C[m][n] = sum_f A[m][f] * W[n][f] + bias[n]
// M=4096, N=256, K=256. 64x64x64 tiles, 256 threads, 4x4 per thread.
// LDS tiles stored K-outer (transposed) so fragment reads are float4.
// ---------------------------------------------------------------------------
#define BM 64
#define BN 64
#define BKk 64
#define LDP 68   // pad: 68 floats = 272B = 17*16B -> float4-aligned, conflict-light

__global__ __launch_bounds__(256) void outproj_kernel(
    const float* __restrict__ A, const float* __restrict__ W,
    const float* __restrict__ bias, float* __restrict__ C) {
  __shared__ float As[BKk][LDP];
  __shared__ float Ws[BKk][LDP];

  const int nbn = E_ / BN;              // 4
  const int bm = blockIdx.x / nbn;      // 0..63
  const int bn = blockIdx.x % nbn;      // 0..3
  const int tid = threadIdx.x;
  const int tm = tid >> 4, tn = tid & 15;
  const int m0 = tm * 4, n0 = tn * 4;

  float acc[4][4] = {};

  for (int kt = 0; kt < E_; kt += BKk) {
#pragma unroll
    for (int f = 0; f < 4; ++f) {
      int fi = tid + f * 256;       // 0..1023
      int row = fi >> 4;            // 0..63
      int kk  = (fi & 15) << 2;     // 0,4,...,60
      float4 v = *(const float4*)&A[(size_t)(bm * BM + row) * E_ + kt + kk];
      As[kk + 0][row] = v.x; As[kk + 1][row] = v.y;
      As[kk + 2][row] = v.z; As[kk + 3][row] = v.w;
      float4 wv = *(const float4*)&W[(size_t)(bn * BN + row) * E_ + kt + kk];
      Ws[kk + 0][row] = wv.x; Ws[kk + 1][row] = wv.y;
      Ws[kk + 2][row] = wv.z; Ws[kk + 3][row] = wv.w;
    }
    __syncthreads();

#pragma unroll 8
    for (int kk = 0; kk < BKk; ++kk) {
      float4 a = *(const float4*)&As[kk][m0];
      float4 w = *(const float4*)&Ws[kk][n0];
      float ar[4] = {a.x, a.y, a.z, a.w};
      float wr[4] = {w.x, w.y, w.z, w.w};
#pragma unroll
      for (int i = 0; i < 4; ++i)
#pragma unroll
        for (int j = 0; j < 4; ++j)
          acc[i][j] = fmaf(ar[i], wr[j], acc[i][j]);
    }
    __syncthreads();
  }

  float4 bv = *(const float4*)&bias[bn * BN + n0];
  float br[4] = {bv.x, bv.y, bv.z, bv.w};
#pragma unroll
  for (int i = 0; i < 4; ++i) {
    int m = bm * BM + m0 + i;
    float4 outv = make_float4(acc[i][0] + br[0], acc[i][1] + br[1],
                              acc[i][2] + br[2], acc[i][3] + br[3]);
    *(float4*)&C[(size_t)m * E_ + bn * BN + n0] = outv;
  }
}

// ---------------------------------------------------------------------------
extern "C" void kernel_launch(void* const* d_in, const int* in_sizes, int n_in,
                              void* d_out, int out_size, void* d_ws, size_t ws_size,
                              hipStream_t stream) {
  const float* x     = (const float*)d_in[0];
  const int*   mask  = (const int*)d_in[1];
  const float* theta = (const float*)d_in[2];
  const float* W     = (const float*)d_in[3];
  const float* bvec  = (const float*)d_in[4];
  float* out = (float*)d_out;

  float* q  = (float*)d_ws;                       // B*H*S*DK = 1M floats, 4MB
  float* ao = q + (size_t)B_ * S_ * E_;           // attention out, [B][S][E], 4MB

  qgen_kernel<<<(B_ * S_ * E_) / 256, 256, 0, stream>>>(x, theta, q);
  attn_kernel<<<B_ * H_ * 4, 256, 0, stream>>>(q, mask, ao);
  outproj_kernel<<<(B_ * S_ / BM) * (E_ / BN), 256, 0, stream>>>(ao, W, bvec, out);
}

// Round 3
// 166.963 us; speedup vs baseline: 1.4475x; 1.4475x over previous
//
#include <hip/hip_runtime.h>

#define B_ 2
#define S_ 2048
#define E_ 256
#define H_ 32
#define DK_ 8

typedef float f32x4 __attribute__((ext_vector_type(4)));
typedef short short8 __attribute__((ext_vector_type(8)));

// RNE float -> bf16 bits
static __device__ __forceinline__ unsigned short f2bf(float x) {
  unsigned u = __float_as_uint(x);
  unsigned r = (u + 0x7FFFu + ((u >> 16) & 1u)) >> 16;
  return (unsigned short)r;
}
static __device__ __forceinline__ unsigned pk2(float a, float b) {
  return (unsigned)f2bf(a) | ((unsigned)f2bf(b) << 16);
}

// ---------------------------------------------------------------------------
// qgen2: v = cos(x + theta).
//   qb [bh][s][8]  bf16, scaled by SQ = sqrt(1/sqrt(8))   (Q and K)
//   qTb[bh][8][s]  bf16, unscaled                          (V, transposed)
// Block: 256 threads over e, 8 s-rows per block. Grid 512.
// ---------------------------------------------------------------------------
__global__ __launch_bounds__(256) void qgen2(
    const float* __restrict__ x, const float* __restrict__ theta,
    unsigned short* __restrict__ qb, unsigned short* __restrict__ qTb) {
  const int blk = blockIdx.x;
  const int b = blk >> 8;          // S_/8 = 256 chunks per batch
  const int s0 = (blk & 255) * 8;
  const int e = threadIdx.x;
  const int h = e >> 3, d = e & 7;
  const float th = theta[d];
  const float SQ = 0.59460355750f; // sqrt(1/sqrt(8)); score*SQ^2 = score/sqrt(8)

  unsigned short tv[8];
#pragma unroll
  for (int r = 0; r < 8; ++r) {
    float v = __cosf(x[((size_t)(b * S_) + s0 + r) * E_ + e] + th);
    qb[((size_t)((b * H_ + h) * S_) + s0 + r) * DK_ + d] = f2bf(v * SQ);
    tv[r] = f2bf(v);
  }
  size_t tb = ((size_t)(b * H_ + h) * DK_ + d) * (size_t)S_ + s0;
  ushort4 w0, w1;
  w0.x = tv[0]; w0.y = tv[1]; w0.z = tv[2]; w0.w = tv[3];
  w1.x = tv[4]; w1.y = tv[5]; w1.z = tv[6]; w1.w = tv[7];
  *(ushort4*)(qTb + tb) = w0;
  *(ushort4*)(qTb + tb + 4) = w1;
}

// ---------------------------------------------------------------------------
// attn2: MFMA attention. Block = 256 thr (4 waves), covers 256 q-rows of one
// (b,h). Grid = 64 bh * 8 = 512 blocks. LDS: full K (bf16, [2048][8]) +
// full K^T (bf16, [8][2056] padded) + bias f32 [2048] + per-wave P buffer.
// Per wave: 4 q-tiles of 16 rows. k-loop: 64 iters of 32 keys, no barriers.
//   QK^T (swapped): S^T = mfma(A=K, B=Q)   (zero-padded k>=8 via B)
//   P = exp(S^T + bias), pack bf16, wave-private LDS regroup
//   O'^T += mfma(A=V'^T, B=P^T), V' has a ones column (n=8) -> denominator
// ---------------------------------------------------------------------------
__global__ __launch_bounds__(256) void attn2(
    const unsigned short* __restrict__ qb, const unsigned short* __restrict__ qTb,
    const int* __restrict__ mask, float* __restrict__ ao) {
  __shared__ float4 K4[S_];            // 32 KB: row s = 8 bf16 = 16B
  __shared__ float4 KT4[DK_ * 257];    // 32.9 KB: row d = 2056 bf16 (pad 8)
  __shared__ float  biasS[S_];         // 8 KB
  __shared__ uint4  P4[4][80];         // per-wave 16 rows x 5 uint4 (20 words)

  const int bh = blockIdx.x >> 3;
  const int qblk = (blockIdx.x & 7) * 256;
  const int b = bh >> 5, h = bh & 31;
  const int tid = threadIdx.x;

  // ---- stage (coalesced, linear) ----
  const float4* qbv = (const float4*)(qb + (size_t)bh * S_ * DK_);
  for (int i = tid; i < S_; i += 256) K4[i] = qbv[i];
  const float4* qtv = (const float4*)(qTb + (size_t)bh * S_ * DK_);
  for (int j = tid; j < S_ * DK_ / 8; j += 256) {  // 2048 float4
    int dd = j >> 8, cj = j & 255;
    KT4[dd * 257 + cj] = qtv[j];
  }
  const int* mb = mask + b * S_;
  for (int i = tid; i < S_; i += 256) biasS[i] = mb[i] ? 0.0f : -1.0e9f;
  __syncthreads();

  const int wid = tid >> 6, lane = tid & 63;
  const int c = lane & 15, g = lane >> 4;

  const float4 zero4 = make_float4(0.f, 0.f, 0.f, 0.f);
  uint4 onesu; onesu.x = 0x3F803F80u; onesu.y = 0x3F803F80u;
  onesu.z = 0x3F803F80u; onesu.w = 0x3F803F80u;

  // Q fragments (B operand): lanes >= 16 must be zero (k >= 8 padding)
  const int qrow0 = qblk + wid * 64;
  short8 qf[4];
  f32x4 acc[4];
#pragma unroll
  for (int qt = 0; qt < 4; ++qt) {
    float4 t = zero4;
    if (lane < 16) t = K4[qrow0 + qt * 16 + lane];
    qf[qt] = __builtin_bit_cast(short8, t);
    acc[qt] = (f32x4){0.f, 0.f, 0.f, 0.f};
  }

  unsigned* Pw = (unsigned*)P4[wid];
  const f32x4 zf = {0.f, 0.f, 0.f, 0.f};

  for (int kt = 0; kt < 64; ++kt) {
    // A fragments (K rows = keys); lanes>=16 carry junk k>=8, killed by B=0
    float4 a0 = K4[kt * 32 + c];
    float4 a1 = K4[kt * 32 + 16 + c];
    // V'^T fragment: row n = c, keys kt*32 + g*8 .. +7
    float4 vt;
    if (c < 8)        vt = KT4[c * 257 + kt * 4 + g];
    else if (c == 8)  vt = __builtin_bit_cast(float4, onesu);
    else              vt = zero4;
    float4 bias0 = *(const float4*)&biasS[kt * 32 + g * 4];
    float4 bias1 = *(const float4*)&biasS[kt * 32 + 16 + g * 4];

    short8 aK0 = __builtin_bit_cast(short8, a0);
    short8 aK1 = __builtin_bit_cast(short8, a1);
    short8 aV  = __builtin_bit_cast(short8, vt);

#pragma unroll
    for (int qt = 0; qt < 4; ++qt) {
      f32x4 s0 = __builtin_amdgcn_mfma_f32_16x16x32_bf16(aK0, qf[qt], zf, 0, 0, 0);
      f32x4 s1 = __builtin_amdgcn_mfma_f32_16x16x32_bf16(aK1, qf[qt], zf, 0, 0, 0);
      // P = exp(score + bias); keys f*16 + 4g + i, qrow c
      unsigned w0 = pk2(__expf(s0[0] + bias0.x), __expf(s0[1] + bias0.y));
      unsigned w1 = pk2(__expf(s0[2] + bias0.z), __expf(s0[3] + bias0.w));
      unsigned w2 = pk2(__expf(s1[0] + bias1.x), __expf(s1[1] + bias1.y));
      unsigned w3 = pk2(__expf(s1[2] + bias1.z), __expf(s1[3] + bias1.w));
      // word index: key-pair kp = 8f + 2g + w, row c, stride 20 words
      Pw[c * 20 + 2 * g]         = w0;
      Pw[c * 20 + 2 * g + 1]     = w1;
      Pw[c * 20 + 8 + 2 * g]     = w2;
      Pw[c * 20 + 8 + 2 * g + 1] = w3;
      // B-frag read: row n = c (this lane's qrow), words 4g'..4g'+3
      uint4 pr = P4[wid][c * 5 + g];
      acc[qt] = __builtin_amdgcn_mfma_f32_16x16x32_bf16(
          aV, __builtin_bit_cast(short8, pr), acc[qt], 0, 0, 0);
    }
  }

  // ---- epilogue: acc[qt] holds O'^T dims m = 4g+i for qrow c.
  // den = dim 8 -> lane 32+c, reg 0. num = dims 0..7 -> lanes g=0,1.
#pragma unroll
  for (int qt = 0; qt < 4; ++qt) {
    float den = __shfl(acc[qt][0], 32 + c);
    float rd = 1.0f / den;
    if (g < 2) {
      int qrow = qrow0 + qt * 16 + c;
      float4 o;
      o.x = acc[qt][0] * rd; o.y = acc[qt][1] * rd;
      o.z = acc[qt][2] * rd; o.w = acc[qt][3] * rd;
      *(float4*)&ao[((size_t)(b * S_ + qrow)) * E_ + h * DK_ + g * 4] = o;
    }
  }
}

// ---------------------------------------------------------------------------
// Kernel 3: C[m][n] = sum_f A[m][f] * W[n][f] + bias[n]   (unchanged)
// ---------------------------------------------------------------------------
#define BM 64
#define BN 64
#define BKk 64
#define LDP 68

__global__ __launch_bounds__(256) void outproj_kernel(
    const float* __restrict__ A, const float* __restrict__ W,
    const float* __restrict__ bias, float* __restrict__ C) {
  __shared__ float As[BKk][LDP];
  __shared__ float Ws[BKk][LDP];

  const int nbn = E_ / BN;
  const int bm = blockIdx.x / nbn;
  const int bn = blockIdx.x % nbn;
  const int tid = threadIdx.x;
  const int tm = tid >> 4, tn = tid & 15;
  const int m0 = tm * 4, n0 = tn * 4;

  float acc[4][4] = {};

  for (int kt = 0; kt < E_; kt += BKk) {
#pragma unroll
    for (int f = 0; f < 4; ++f) {
      int fi = tid + f * 256;
      int row = fi >> 4;
      int kk = (fi & 15) << 2;
      float4 v = *(const float4*)&A[(size_t)(bm * BM + row) * E_ + kt + kk];
      As[kk + 0][row] = v.x; As[kk + 1][row] = v.y;
      As[kk + 2][row] = v.z; As[kk + 3][row] = v.w;
      float4 wv = *(const float4*)&W[(size_t)(bn * BN + row) * E_ + kt + kk];
      Ws[kk + 0][row] = wv.x; Ws[kk + 1][row] = wv.y;
      Ws[kk + 2][row] = wv.z; Ws[kk + 3][row] = wv.w;
    }
    __syncthreads();

#pragma unroll 8
    for (int kk = 0; kk < BKk; ++kk) {
      float4 a = *(const float4*)&As[kk][m0];
      float4 w = *(const float4*)&Ws[kk][n0];
      float ar[4] = {a.x, a.y, a.z, a.w};
      float wr[4] = {w.x, w.y, w.z, w.w};
#pragma unroll
      for (int i = 0; i < 4; ++i)
#pragma unroll
        for (int j = 0; j < 4; ++j)
          acc[i][j] = fmaf(ar[i], wr[j], acc[i][j]);
    }
    __syncthreads();
  }

  float4 bv = *(const float4*)&bias[bn * BN + n0];
  float br[4] = {bv.x, bv.y, bv.z, bv.w};
#pragma unroll
  for (int i = 0; i < 4; ++i) {
    int m = bm * BM + m0 + i;
    float4 outv = make_float4(acc[i][0] + br[0], acc[i][1] + br[1],
                              acc[i][2] + br[2], acc[i][3] + br[3]);
    *(float4*)&C[(size_t)m * E_ + bn * BN + n0] = outv;
  }
}

// ---------------------------------------------------------------------------
extern "C" void kernel_launch(void* const* d_in, const int* in_sizes, int n_in,
                              void* d_out, int out_size, void* d_ws, size_t ws_size,
                              hipStream_t stream) {
  const float* x     = (const float*)d_in[0];
  const int*   mask  = (const int*)d_in[1];
  const float* theta = (const float*)d_in[2];
  const float* W     = (const float*)d_in[3];
  const float* bvec  = (const float*)d_in[4];
  float* out = (float*)d_out;

  unsigned short* qbb = (unsigned short*)d_ws;                 // 2 MB bf16
  unsigned short* qTb = qbb + (size_t)B_ * H_ * S_ * DK_;      // 2 MB bf16
  float* ao = (float*)(qTb + (size_t)B_ * H_ * S_ * DK_);      // 4 MB f32

  qgen2<<<512, 256, 0, stream>>>(x, theta, qbb, qTb);
  attn2<<<B_ * H_ * 8, 256, 0, stream>>>(qbb, qTb, mask, ao);
  outproj_kernel<<<(B_ * S_ / BM) * (E_ / BN), 256, 0, stream>>>(ao, W, bvec, out);
}

// Round 4
// 134.993 us; speedup vs baseline: 1.7903x; 1.2368x over previous
//
#include <hip/hip_runtime.h>

#define B_ 2
#define S_ 2048
#define E_ 256
#define H_ 32
#define DK_ 8

typedef float f32x4 __attribute__((ext_vector_type(4)));
typedef short short8 __attribute__((ext_vector_type(8)));
typedef unsigned short us8 __attribute__((ext_vector_type(8)));

// scale folded into q: score*SQ^2 = (q.k) * log2(e)/sqrt(8)  -> exp2 arg
#define SQ_ 0.71419638f
// bf16(SQ) used for the ones-column of V'
#define CONES_F 0.71484375f
#define CONES_BITS 0x3F373F37u
#define CORR_ (CONES_F / SQ_)   // epilogue correction C/SQ

// RNE float -> bf16 bits (host-quality path for qgen)
static __device__ __forceinline__ unsigned short f2bf(float x) {
  unsigned u = __float_as_uint(x);
  return (unsigned short)((u + 0x7FFFu + ((u >> 16) & 1u)) >> 16);
}

static __device__ __forceinline__ float ex2(float x) {
#if __has_builtin(__builtin_amdgcn_exp2f)
  return __builtin_amdgcn_exp2f(x);
#else
  float r; asm("v_exp_f32 %0, %1\n\ts_nop 0" : "=v"(r) : "v"(x)); return r;
#endif
}

static __device__ __forceinline__ unsigned cvtpk(float lo, float hi) {
  unsigned r;
  asm("v_cvt_pk_bf16_f32 %0, %1, %2" : "=v"(r) : "v"(lo), "v"(hi));
  return r;
}

// ---------------------------------------------------------------------------
// qgen3: q[b][h][s][d] = cos(x[b][s][h*8+d] + theta[d]) * SQ, bf16.
// LDS transpose so both the x read and the qb write are coalesced.
// Grid 256 blocks x 256 thr; each block does 16 s-rows x 256 e.
// ---------------------------------------------------------------------------
__global__ __launch_bounds__(256) void qgen3(
    const float* __restrict__ x, const float* __restrict__ theta,
    unsigned short* __restrict__ qb) {
  __shared__ unsigned short TL[16][264];   // [row][e], pad 8 shorts

  const int tid = threadIdx.x;
  const int gs = blockIdx.x * 16;          // global row base over B*S
  const int b = gs >> 11, s0 = gs & (S_ - 1);

  float th[8];
#pragma unroll
  for (int d = 0; d < 8; ++d) th[d] = theta[d];

#pragma unroll
  for (int p = 0; p < 4; ++p) {
    int fi = tid + p * 256;                // 0..1023
    int row = fi >> 6, col4 = fi & 63;
    float4 v = *(const float4*)&x[((size_t)(b * S_ + s0 + row)) * E_ + col4 * 4];
    int dbase = (col4 & 1) * 4;
    unsigned w0 = (unsigned)f2bf(__cosf(v.x + th[dbase + 0]) * SQ_) |
                  ((unsigned)f2bf(__cosf(v.y + th[dbase + 1]) * SQ_) << 16);
    unsigned w1 = (unsigned)f2bf(__cosf(v.z + th[dbase + 2]) * SQ_) |
                  ((unsigned)f2bf(__cosf(v.w + th[dbase + 3]) * SQ_) << 16);
    uint2 wv; wv.x = w0; wv.y = w1;
    *(uint2*)&TL[row][col4 * 4] = wv;
  }
  __syncthreads();

  const int h = tid >> 3, part = tid & 7;
#pragma unroll
  for (int i = 0; i < 2; ++i) {
    int r = part * 2 + i;
    uint4 t = *(uint4*)&TL[r][h * 8];
    *(uint4*)&qb[((size_t)(b * H_ + h) * S_ + s0 + r) * DK_] = t;
  }
}

// ---------------------------------------------------------------------------
// attn3: MFMA attention, in-register softmax regroup (cvt_pk + permlane).
// Block = 256 thr (4 waves) = 256 q-rows of one (b,h); grid 512.
// LDS: K [2048][8] bf16 (32KB) + V'^T [8][2056] bf16 (33KB) + bias f32 (8KB).
// k-loop: 64 iters x 32 keys, ZERO barriers, ZERO LDS in softmax path.
// ---------------------------------------------------------------------------
__global__ __launch_bounds__(256) void attn3(
    const unsigned short* __restrict__ qb, const int* __restrict__ mask,
    float* __restrict__ ao) {
  __shared__ float4 K4[S_];                     // 32 KB
  __shared__ unsigned short KTs[DK_ * 2056];    // 32.9 KB (pad 8/row)
  __shared__ float biasS[S_];                   // 8 KB

  const int bh = blockIdx.x >> 3;
  const int qblk = (blockIdx.x & 7) * 256;
  const int b = bh >> 5, h = bh & 31;
  const int tid = threadIdx.x;

  // ---- stage: K linear + V'^T transposed (paired rows -> b32 writes) ----
  const float4* qbv = (const float4*)(qb + (size_t)bh * S_ * DK_);
#pragma unroll
  for (int p = 0; p < 4; ++p) {
    int rp = tid + p * 256;        // 0..1023 -> rows 2rp, 2rp+1
    int s = rp * 2;
    float4 f0 = qbv[s], f1 = qbv[s + 1];
    K4[s] = f0; K4[s + 1] = f1;
    us8 u0 = __builtin_bit_cast(us8, f0);
    us8 u1 = __builtin_bit_cast(us8, f1);
#pragma unroll
    for (int d = 0; d < 8; ++d) {
      unsigned wv = (unsigned)u0[d] | ((unsigned)u1[d] << 16);
      *(unsigned*)&KTs[d * 2056 + s] = wv;
    }
  }
  const int* mb = mask + b * S_;
  for (int i = tid; i < S_; i += 256) biasS[i] = mb[i] ? 0.0f : -1.0e9f;
  __syncthreads();

  const int wid = tid >> 6, lane = tid & 63;
  const int c = lane & 15, g = lane >> 4;

  const float4 zero4 = make_float4(0.f, 0.f, 0.f, 0.f);
  uint4 cpat; cpat.x = CONES_BITS; cpat.y = CONES_BITS;
  cpat.z = CONES_BITS; cpat.w = CONES_BITS;

  // Q fragments (B operand): lanes >= 16 zero (k >= 8 padding)
  const int qrow0 = qblk + wid * 64;
  short8 qf[4];
  f32x4 acc[4];
#pragma unroll
  for (int qt = 0; qt < 4; ++qt) {
    float4 t = zero4;
    if (lane < 16) t = K4[qrow0 + qt * 16 + lane];
    qf[qt] = __builtin_bit_cast(short8, t);
    acc[qt] = (f32x4){0.f, 0.f, 0.f, 0.f};
  }

  const f32x4 zf = {0.f, 0.f, 0.f, 0.f};

  for (int kt = 0; kt < 64; ++kt) {
    float4 a0f = K4[kt * 32 + c];
    float4 a1f = K4[kt * 32 + 16 + c];
    float4 vtf;
    if (c < 8)       vtf = *(const float4*)&KTs[c * 2056 + kt * 32 + 8 * g];
    else if (c == 8) vtf = __builtin_bit_cast(float4, cpat);
    else             vtf = zero4;
    float4 bias0 = *(const float4*)&biasS[kt * 32 + g * 4];
    float4 bias1 = *(const float4*)&biasS[kt * 32 + 16 + g * 4];

    short8 aK0 = __builtin_bit_cast(short8, a0f);
    short8 aK1 = __builtin_bit_cast(short8, a1f);
    short8 aV  = __builtin_bit_cast(short8, vtf);

#pragma unroll
    for (int qt = 0; qt < 4; ++qt) {
      f32x4 s0 = __builtin_amdgcn_mfma_f32_16x16x32_bf16(aK0, qf[qt], zf, 0, 0, 0);
      f32x4 s1 = __builtin_amdgcn_mfma_f32_16x16x32_bf16(aK1, qf[qt], zf, 0, 0, 0);
      // P = exp2(score + bias), packed to bf16 pairs
      unsigned w0 = cvtpk(ex2(s0[0] + bias0.x), ex2(s0[1] + bias0.y));
      unsigned w1 = cvtpk(ex2(s0[2] + bias0.z), ex2(s0[3] + bias0.w));
      unsigned w2 = cvtpk(ex2(s1[0] + bias1.x), ex2(s1[1] + bias1.y));
      unsigned w3 = cvtpk(ex2(s1[2] + bias1.z), ex2(s1[3] + bias1.w));
      // in-register regroup: lane (c,g) key-pairs -> lane (c,g') key runs
      asm("v_permlane32_swap_b32 %0, %1" : "+v"(w0), "+v"(w2));
      asm("v_permlane16_swap_b32 %0, %1" : "+v"(w0), "+v"(w2));
      asm("v_permlane32_swap_b32 %0, %1" : "+v"(w1), "+v"(w3));
      asm("v_permlane16_swap_b32 %0, %1" : "+v"(w1), "+v"(w3));
      uint4 pu; pu.x = w0; pu.y = w1; pu.z = w2; pu.w = w3;
      acc[qt] = __builtin_amdgcn_mfma_f32_16x16x32_bf16(
          aV, __builtin_bit_cast(short8, pu), acc[qt], 0, 0, 0);
    }
  }

  // ---- epilogue: rows m=0..7 -> numerator dims, m=8 -> denominator*C ----
#pragma unroll
  for (int qt = 0; qt < 4; ++qt) {
    float den = __shfl(acc[qt][0], 32 + c);   // lane g=2 holds m=8 in reg 0
    float rd = CORR_ / den;
    if (g < 2) {
      int qrow = qrow0 + qt * 16 + c;
      float4 o;
      o.x = acc[qt][0] * rd; o.y = acc[qt][1] * rd;
      o.z = acc[qt][2] * rd; o.w = acc[qt][3] * rd;
      *(float4*)&ao[((size_t)(b * S_ + qrow)) * E_ + h * DK_ + g * 4] = o;
    }
  }
}

// ---------------------------------------------------------------------------
// Kernel 3: C[m][n] = sum_f A[m][f] * W[n][f] + bias[n]   (unchanged)
// ---------------------------------------------------------------------------
#define BM 64
#define BN 64
#define BKk 64
#define LDP 68

__global__ __launch_bounds__(256) void outproj_kernel(
    const float* __restrict__ A, const float* __restrict__ W,
    const float* __restrict__ bias, float* __restrict__ C) {
  __shared__ float As[BKk][LDP];
  __shared__ float Ws[BKk][LDP];

  const int nbn = E_ / BN;
  const int bm = blockIdx.x / nbn;
  const int bn = blockIdx.x % nbn;
  const int tid = threadIdx.x;
  const int tm = tid >> 4, tn = tid & 15;
  const int m0 = tm * 4, n0 = tn * 4;

  float acc[4][4] = {};

  for (int kt = 0; kt < E_; kt += BKk) {
#pragma unroll
    for (int f = 0; f < 4; ++f) {
      int fi = tid + f * 256;
      int row = fi >> 4;
      int kk = (fi & 15) << 2;
      float4 v = *(const float4*)&A[(size_t)(bm * BM + row) * E_ + kt + kk];
      As[kk + 0][row] = v.x; As[kk + 1][row] = v.y;
      As[kk + 2][row] = v.z; As[kk + 3][row] = v.w;
      float4 wv = *(const float4*)&W[(size_t)(bn * BN + row) * E_ + kt + kk];
      Ws[kk + 0][row] = wv.x; Ws[kk + 1][row] = wv.y;
      Ws[kk + 2][row] = wv.z; Ws[kk + 3][row] = wv.w;
    }
    __syncthreads();

#pragma unroll 8
    for (int kk = 0; kk < BKk; ++kk) {
      float4 a = *(const float4*)&As[kk][m0];
      float4 w = *(const float4*)&Ws[kk][n0];
      float ar[4] = {a.x, a.y, a.z, a.w};
      float wr[4] = {w.x, w.y, w.z, w.w};
#pragma unroll
      for (int i = 0; i < 4; ++i)
#pragma unroll
        for (int j = 0; j < 4; ++j)
          acc[i][j] = fmaf(ar[i], wr[j], acc[i][j]);
    }
    __syncthreads();
  }

  float4 bv = *(const float4*)&bias[bn * BN + n0];
  float br[4] = {bv.x, bv.y, bv.z, bv.w};
#pragma unroll
  for (int i = 0; i < 4; ++i) {
    int m = bm * BM + m0 + i;
    float4 outv = make_float4(acc[i][0] + br[0], acc[i][1] + br[1],
                              acc[i][2] + br[2], acc[i][3] + br[3]);
    *(float4*)&C[(size_t)m * E_ + bn * BN + n0] = outv;
  }
}

// ---------------------------------------------------------------------------
extern "C" void kernel_launch(void* const* d_in, const int* in_sizes, int n_in,
                              void* d_out, int out_size, void* d_ws, size_t ws_size,
                              hipStream_t stream) {
  const float* x     = (const float*)d_in[0];
  const int*   mask  = (const int*)d_in[1];
  const float* theta = (const float*)d_in[2];
  const float* W     = (const float*)d_in[3];
  const float* bvec  = (const float*)d_in[4];
  float* out = (float*)d_out;

  unsigned short* qbb = (unsigned short*)d_ws;             // 2 MB bf16
  float* ao = (float*)(qbb + (size_t)B_ * H_ * S_ * DK_);  // 4 MB f32

  qgen3<<<256, 256, 0, stream>>>(x, theta, qbb);
  attn3<<<B_ * H_ * 8, 256, 0, stream>>>(qbb, mask, ao);
  outproj_kernel<<<(B_ * S_ / BM) * (E_ / BN), 256, 0, stream>>>(ao, W, bvec, out);
}

// Round 5
// 130.241 us; speedup vs baseline: 1.8556x; 1.0365x over previous
//
#include <hip/hip_runtime.h>

#define B_ 2
#define S_ 2048
#define E_ 256
#define H_ 32
#define DK_ 8

typedef float f32x4 __attribute__((ext_vector_type(4)));
typedef short short8 __attribute__((ext_vector_type(8)));
typedef unsigned short us8 __attribute__((ext_vector_type(8)));

// scale folded into q: (q*SQ).(k*SQ) = (q.k) * log2(e)/sqrt(8)  -> exp2 arg
#define SQ_ 0.71419638f
// bf16(SQ) used for the ones-column of V'
#define CONES_F 0.71484375f
#define CONES_BITS 0x3F373F37u
#define CORR_ (CONES_F / SQ_)   // epilogue correction C/SQ

static __device__ __forceinline__ float ex2(float x) {
#if __has_builtin(__builtin_amdgcn_exp2f)
  return __builtin_amdgcn_exp2f(x);
#else
  float r; asm("v_exp_f32 %0, %1\n\ts_nop 0" : "=v"(r) : "v"(x)); return r;
#endif
}

static __device__ __forceinline__ unsigned cvtpk(float lo, float hi) {
  unsigned r;
  asm("v_cvt_pk_bf16_f32 %0, %1, %2" : "=v"(r) : "v"(lo), "v"(hi));
  return r;
}

// ---------------------------------------------------------------------------
// qgen4: qb[b][h][s][d] = bf16( cos(x[b][s][h*8+d] + theta[d]) * SQ ).
// LDS transpose; grid 512 x 256 thr, 8 s-rows per block.
// ---------------------------------------------------------------------------
__global__ __launch_bounds__(256) void qgen4(
    const float* __restrict__ x, const float* __restrict__ theta,
    unsigned short* __restrict__ qb) {
  __shared__ unsigned short TL[8][264];

  const int tid = threadIdx.x;
  const int gs = blockIdx.x * 8;
  const int b = gs >> 11, s0 = gs & (S_ - 1);

  float th[8];
#pragma unroll
  for (int d = 0; d < 8; ++d) th[d] = theta[d];

#pragma unroll
  for (int p = 0; p < 2; ++p) {
    int fi = tid + p * 256;                 // 0..511
    int row = fi >> 6, col4 = fi & 63;
    float4 v = *(const float4*)&x[((size_t)(b * S_ + s0 + row)) * E_ + col4 * 4];
    int dbase = (col4 & 1) * 4;
    uint2 wv;
    wv.x = cvtpk(__cosf(v.x + th[dbase + 0]) * SQ_,
                 __cosf(v.y + th[dbase + 1]) * SQ_);
    wv.y = cvtpk(__cosf(v.z + th[dbase + 2]) * SQ_,
                 __cosf(v.w + th[dbase + 3]) * SQ_);
    *(uint2*)&TL[row][col4 * 4] = wv;
  }
  __syncthreads();

  const int h = tid >> 3, r = tid & 7;
  uint4 t = *(uint4*)&TL[r][h * 8];
  *(uint4*)&qb[((size_t)(b * H_ + h) * S_ + s0 + r) * DK_] = t;
}

// ---------------------------------------------------------------------------
// attn4: MFMA attention, 2-pass K staging (1024 keys each), 35 KB LDS.
// Grid 1024: bh (64) x q-chunk (16 x 128 rows). Block 256 thr = 4 waves,
// wave covers 32 q-rows (2 x 16-row tiles). In-register softmax regroup.
// Fast path when the mask chunk is all ones: no bias work at all.
// ---------------------------------------------------------------------------
__global__ __launch_bounds__(256) void attn4(
    const unsigned short* __restrict__ qb, const int* __restrict__ mask,
    float* __restrict__ ao) {
  __shared__ float4 K4[1024];                   // 16 KB
  __shared__ unsigned short KTs[DK_ * 1040];    // 16.6 KB (stride 1040)
  __shared__ unsigned Mk[512];                  // 2 KB packed key-pair masks
  __shared__ int sOK[4];

  const int bh = blockIdx.x >> 4;
  const int qblk = (blockIdx.x & 15) * 128;
  const int b = bh >> 5, h = bh & 31;
  const int tid = threadIdx.x;
  const int wid = tid >> 6, lane = tid & 63;
  const int c = lane & 15, g = lane >> 4;

  const float4 zero4 = make_float4(0.f, 0.f, 0.f, 0.f);
  uint4 cpat; cpat.x = CONES_BITS; cpat.y = CONES_BITS;
  cpat.z = CONES_BITS; cpat.w = CONES_BITS;

  const float4* qbv = (const float4*)(qb + (size_t)bh * S_ * DK_);

  // Q fragments from global (qb is L2-resident); lanes >= 16 zero (k>=8 pad)
  const int qrow0 = qblk + wid * 32;
  short8 qf[2];
  f32x4 acc[2];
#pragma unroll
  for (int qt = 0; qt < 2; ++qt) {
    float4 t = zero4;
    if (lane < 16) t = qbv[qrow0 + qt * 16 + lane];
    qf[qt] = __builtin_bit_cast(short8, t);
    acc[qt] = (f32x4){0.f, 0.f, 0.f, 0.f};
  }

  const f32x4 zf = {0.f, 0.f, 0.f, 0.f};

#define KLOOP(MASKED)                                                        \
  for (int kt = 0; kt < 32; ++kt) {                                          \
    float4 a0f = K4[kt * 32 + c];                                            \
    float4 a1f = K4[kt * 32 + 16 + c];                                       \
    float4 vtf;                                                              \
    if (c < 8)       vtf = *(const float4*)&KTs[c * 1040 + kt * 32 + 8 * g]; \
    else if (c == 8) vtf = __builtin_bit_cast(float4, cpat);                 \
    else             vtf = zero4;                                            \
    uint2 mA, mB;                                                            \
    if (MASKED) {                                                            \
      mA = *(const uint2*)&Mk[kt * 16 + 2 * g];                              \
      mB = *(const uint2*)&Mk[kt * 16 + 8 + 2 * g];                          \
    }                                                                        \
    short8 aK0 = __builtin_bit_cast(short8, a0f);                            \
    short8 aK1 = __builtin_bit_cast(short8, a1f);                            \
    short8 aV  = __builtin_bit_cast(short8, vtf);                            \
    _Pragma("unroll")                                                        \
    for (int qt = 0; qt < 2; ++qt) {                                         \
      f32x4 s0 = __builtin_amdgcn_mfma_f32_16x16x32_bf16(aK0, qf[qt], zf, 0, 0, 0); \
      f32x4 s1 = __builtin_amdgcn_mfma_f32_16x16x32_bf16(aK1, qf[qt], zf, 0, 0, 0); \
      unsigned w0 = cvtpk(ex2(s0[0]), ex2(s0[1]));                           \
      unsigned w1 = cvtpk(ex2(s0[2]), ex2(s0[3]));                           \
      unsigned w2 = cvtpk(ex2(s1[0]), ex2(s1[1]));                           \
      unsigned w3 = cvtpk(ex2(s1[2]), ex2(s1[3]));                           \
      if (MASKED) { w0 &= mA.x; w1 &= mA.y; w2 &= mB.x; w3 &= mB.y; }        \
      asm("v_permlane32_swap_b32 %0, %1" : "+v"(w0), "+v"(w2));              \
      asm("v_permlane16_swap_b32 %0, %1" : "+v"(w0), "+v"(w2));              \
      asm("v_permlane32_swap_b32 %0, %1" : "+v"(w1), "+v"(w3));              \
      asm("v_permlane16_swap_b32 %0, %1" : "+v"(w1), "+v"(w3));              \
      uint4 pu; pu.x = w0; pu.y = w1; pu.z = w2; pu.w = w3;                  \
      acc[qt] = __builtin_amdgcn_mfma_f32_16x16x32_bf16(                     \
          aV, __builtin_bit_cast(short8, pu), acc[qt], 0, 0, 0);             \
    }                                                                        \
  }

#pragma unroll 1
  for (int p = 0; p < 2; ++p) {
    if (p) __syncthreads();               // all waves done with pass p-1 data
    const float4* src = qbv + p * 1024;
#pragma unroll
    for (int it = 0; it < 2; ++it) {
      int rp = tid + it * 256;            // 0..511 -> rows 2rp, 2rp+1
      int s = rp * 2;
      float4 f0 = src[s], f1 = src[s + 1];
      K4[s] = f0; K4[s + 1] = f1;
      us8 u0 = __builtin_bit_cast(us8, f0);
      us8 u1 = __builtin_bit_cast(us8, f1);
#pragma unroll
      for (int d = 0; d < 8; ++d) {
        unsigned wv = (unsigned)u0[d] | ((unsigned)u1[d] << 16);
        *(unsigned*)&KTs[d * 1040 + s] = wv;
      }
    }
    const int* mp = mask + b * S_ + p * 1024;
    int4 mv = *(const int4*)&mp[tid * 4];
    int ok = (mv.x != 0) & (mv.y != 0) & (mv.z != 0) & (mv.w != 0);
    Mk[2 * tid]     = (mv.x ? 0xFFFFu : 0u) | (mv.y ? 0xFFFF0000u : 0u);
    Mk[2 * tid + 1] = (mv.z ? 0xFFFFu : 0u) | (mv.w ? 0xFFFF0000u : 0u);
    int wall = __all(ok);
    if (lane == 0) sOK[wid] = wall;
    __syncthreads();
    int allones = sOK[0] & sOK[1] & sOK[2] & sOK[3];

    if (allones) { KLOOP(0) } else { KLOOP(1) }
  }
#undef KLOOP

  // epilogue: rows m=0..7 -> numerator dims, m=8 -> denominator*CONES
#pragma unroll
  for (int qt = 0; qt < 2; ++qt) {
    float den = __shfl(acc[qt][0], 32 + c);
    float rd = CORR_ / den;
    if (g < 2) {
      int qrow = qrow0 + qt * 16 + c;
      float4 o;
      o.x = acc[qt][0] * rd; o.y = acc[qt][1] * rd;
      o.z = acc[qt][2] * rd; o.w = acc[qt][3] * rd;
      *(float4*)&ao[((size_t)(b * S_ + qrow)) * E_ + h * DK_ + g * 4] = o;
    }
  }
}

// ---------------------------------------------------------------------------
// outproj2: C[m][n] = sum_f A[m][f]*W[n][f] + bias[n].  M=4096,N=256,K=256.
// BM=32, BN=64 -> grid 512 (2 blocks/CU). 256 thr, 2x4 micro-tile.
// ---------------------------------------------------------------------------
__global__ __launch_bounds__(256) void outproj2(
    const float* __restrict__ A, const float* __restrict__ W,
    const float* __restrict__ bias, float* __restrict__ C) {
  __shared__ float As[64][36];
  __shared__ float Ws[64][68];

  const int bm = blockIdx.x >> 2;       // 0..127
  const int bn = blockIdx.x & 3;        // 0..3
  const int tid = threadIdx.x;
  const int tm = tid >> 4, tn = tid & 15;
  const int m0 = tm * 2, n0 = tn * 4;

  float acc[2][4] = {};

  for (int kt = 0; kt < E_; kt += 64) {
#pragma unroll
    for (int f = 0; f < 2; ++f) {
      int fi = tid + f * 256;           // 0..511
      int row = fi >> 4;                // 0..31
      int kk = (fi & 15) << 2;
      float4 v = *(const float4*)&A[(size_t)(bm * 32 + row) * E_ + kt + kk];
      As[kk + 0][row] = v.x; As[kk + 1][row] = v.y;
      As[kk + 2][row] = v.z; As[kk + 3][row] = v.w;
    }
#pragma unroll
    for (int f = 0; f < 4; ++f) {
      int fi = tid + f * 256;           // 0..1023
      int row = fi >> 4;                // 0..63
      int kk = (fi & 15) << 2;
      float4 wv = *(const float4*)&W[(size_t)(bn * 64 + row) * E_ + kt + kk];
      Ws[kk + 0][row] = wv.x; Ws[kk + 1][row] = wv.y;
      Ws[kk + 2][row] = wv.z; Ws[kk + 3][row] = wv.w;
    }
    __syncthreads();

#pragma unroll 8
    for (int kk = 0; kk < 64; ++kk) {
      float2 a = *(const float2*)&As[kk][m0];
      float4 w = *(const float4*)&Ws[kk][n0];
      float ar[2] = {a.x, a.y};
      float wr[4] = {w.x, w.y, w.z, w.w};
#pragma unroll
      for (int i = 0; i < 2; ++i)
#pragma unroll
        for (int j = 0; j < 4; ++j)
          acc[i][j] = fmaf(ar[i], wr[j], acc[i][j]);
    }
    __syncthreads();
  }

  float4 bv = *(const float4*)&bias[bn * 64 + n0];
  float br[4] = {bv.x, bv.y, bv.z, bv.w};
#pragma unroll
  for (int i = 0; i < 2; ++i) {
    int m = bm * 32 + m0 + i;
    float4 outv = make_float4(acc[i][0] + br[0], acc[i][1] + br[1],
                              acc[i][2] + br[2], acc[i][3] + br[3]);
    *(float4*)&C[(size_t)m * E_ + bn * 64 + n0] = outv;
  }
}

// ---------------------------------------------------------------------------
extern "C" void kernel_launch(void* const* d_in, const int* in_sizes, int n_in,
                              void* d_out, int out_size, void* d_ws, size_t ws_size,
                              hipStream_t stream) {
  const float* x     = (const float*)d_in[0];
  const int*   mask  = (const int*)d_in[1];
  const float* theta = (const float*)d_in[2];
  const float* W     = (const float*)d_in[3];
  const float* bvec  = (const float*)d_in[4];
  float* out = (float*)d_out;

  unsigned short* qbb = (unsigned short*)d_ws;             // 2 MB bf16
  float* ao = (float*)(qbb + (size_t)B_ * H_ * S_ * DK_);  // 4 MB f32

  qgen4<<<512, 256, 0, stream>>>(x, theta, qbb);
  attn4<<<1024, 256, 0, stream>>>(qbb, mask, ao);
  outproj2<<<512, 256, 0, stream>>>(ao, W, bvec, out);
}

// Round 8
// 126.000 us; speedup vs baseline: 1.9181x; 1.0337x over previous
//
#include <hip/hip_runtime.h>

#define B_ 2
#define S_ 2048
#define E_ 256
#define H_ 32
#define DK_ 8
#define KTSTR 1036   // uint words per V'-row: 1024 + pad; conflict-free b128 reads

typedef float f32x4 __attribute__((ext_vector_type(4)));
typedef short short8 __attribute__((ext_vector_type(8)));

// scale folded into q: (q*SQ).(k*SQ) = (q.k) * log2(e)/sqrt(8)  -> exp2 arg
#define SQ_ 0.71419638f
// bf16(SQ) used for the ones-column of V'
#define CONES_F 0.71484375f
#define CONES_BITS 0x3F373F37u
#define CORR_ (CONES_F / SQ_)   // epilogue correction C/SQ

static __device__ __forceinline__ float ex2(float x) {
#if __has_builtin(__builtin_amdgcn_exp2f)
  return __builtin_amdgcn_exp2f(x);
#else
  float r; asm("v_exp_f32 %0, %1" : "=v"(r) : "v"(x)); return r;
#endif
}

static __device__ __forceinline__ unsigned cvtpk(float lo, float hi) {
  unsigned r;
  asm("v_cvt_pk_bf16_f32 %0, %1, %2" : "=v"(r) : "v"(lo), "v"(hi));
  return r;
}

// ---------------------------------------------------------------------------
// attn5: fused cos + MFMA attention. Grid 512 = 64 bh x 8 q-chunks.
// Block 256 thr (4 waves); wave owns 64 q-rows (qt=4 x 16).
// LDS: K [2048][8] bf16 (32KB) + V'^T pi-permuted (33KB) + mask words (4KB).
// k-loop: 64 iters x 32 keys, zero barriers, zero cross-lane ops:
//   S^T = mfma(A=K, B=Q); P = exp2(S^T); cvt_pk -> B-frag DIRECTLY
//   (V'^T staged with the matching key-slot permutation); ones-col -> denom.
// ---------------------------------------------------------------------------
__global__ __launch_bounds__(256) void attn5(
    const float* __restrict__ x, const float* __restrict__ theta,
    const int* __restrict__ mask, float* __restrict__ ao) {
  __shared__ float4 K4[S_];                 // 32 KB
  __shared__ unsigned KTu[DK_ * KTSTR];     // 33.2 KB
  __shared__ unsigned Mk[S_ / 2];           // 4 KB packed key-pair masks
  __shared__ int sOK[4];

  const int bh = blockIdx.x >> 3;
  const int qblk = (blockIdx.x & 7) * 256;
  const int b = bh >> 5, h = bh & 31;
  const int tid = threadIdx.x;
  const int wid = tid >> 6, lane = tid & 63;
  const int c = lane & 15, g = lane >> 4;

  const float* xb = x + (size_t)b * S_ * E_ + h * DK_;

  float th[8];
#pragma unroll
  for (int d = 0; d < 8; ++d) th[d] = theta[d];

  // ---- Q fragments (B operand): lanes >= 16 zero (k >= 8 padding) ----
  const int qrow0 = qblk + wid * 64;
  short8 qf[4];
  f32x4 acc[4];
#pragma unroll
  for (int qt = 0; qt < 4; ++qt) {
    acc[qt] = (f32x4){0.f, 0.f, 0.f, 0.f};
    uint4 qq = {0u, 0u, 0u, 0u};
    if (lane < 16) {
      const float* xq = xb + (size_t)(qrow0 + qt * 16 + lane) * E_;
      float4 a = *(const float4*)xq;
      float4 bq = *(const float4*)(xq + 4);
      qq.x = cvtpk(__cosf(a.x + th[0]) * SQ_, __cosf(a.y + th[1]) * SQ_);
      qq.y = cvtpk(__cosf(a.z + th[2]) * SQ_, __cosf(a.w + th[3]) * SQ_);
      qq.z = cvtpk(__cosf(bq.x + th[4]) * SQ_, __cosf(bq.y + th[5]) * SQ_);
      qq.w = cvtpk(__cosf(bq.z + th[6]) * SQ_, __cosf(bq.w + th[7]) * SQ_);
    }
    qf[qt] = __builtin_bit_cast(short8, qq);
  }

  // ---- fused staging: cos + K4 (row-major) + KTu (pi-permuted) + masks ----
  // 1024 key-pairs total, 256 threads -> 4 iterations.
  int okall = 1;
#pragma unroll
  for (int it = 0; it < 4; ++it) {
    int pi = it * 256 + tid;            // key pair 0..1023
    int s = pi * 2;
    const float* xr = xb + (size_t)s * E_;
    float4 v00 = *(const float4*)xr;
    float4 v01 = *(const float4*)(xr + 4);
    float4 v10 = *(const float4*)(xr + E_);
    float4 v11 = *(const float4*)(xr + E_ + 4);
    float c0[8], c1[8];
    c0[0] = __cosf(v00.x + th[0]) * SQ_; c0[1] = __cosf(v00.y + th[1]) * SQ_;
    c0[2] = __cosf(v00.z + th[2]) * SQ_; c0[3] = __cosf(v00.w + th[3]) * SQ_;
    c0[4] = __cosf(v01.x + th[4]) * SQ_; c0[5] = __cosf(v01.y + th[5]) * SQ_;
    c0[6] = __cosf(v01.z + th[6]) * SQ_; c0[7] = __cosf(v01.w + th[7]) * SQ_;
    c1[0] = __cosf(v10.x + th[0]) * SQ_; c1[1] = __cosf(v10.y + th[1]) * SQ_;
    c1[2] = __cosf(v10.z + th[2]) * SQ_; c1[3] = __cosf(v10.w + th[3]) * SQ_;
    c1[4] = __cosf(v11.x + th[4]) * SQ_; c1[5] = __cosf(v11.y + th[5]) * SQ_;
    c1[6] = __cosf(v11.z + th[6]) * SQ_; c1[7] = __cosf(v11.w + th[7]) * SQ_;
    uint4 r0, r1;
    r0.x = cvtpk(c0[0], c0[1]); r0.y = cvtpk(c0[2], c0[3]);
    r0.z = cvtpk(c0[4], c0[5]); r0.w = cvtpk(c0[6], c0[7]);
    r1.x = cvtpk(c1[0], c1[1]); r1.y = cvtpk(c1[2], c1[3]);
    r1.z = cvtpk(c1[4], c1[5]); r1.w = cvtpk(c1[6], c1[7]);
    K4[s]     = __builtin_bit_cast(float4, r0);
    K4[s + 1] = __builtin_bit_cast(float4, r1);
    // pi-permuted word slot within the 16-word (32-key) kt group
    int ktg = pi >> 4, m = pi & 15;
    int w = 4 * ((m & 7) >> 1) + ((m >> 3) << 1) + (m & 1);
    int base = ktg * 16 + w;
#pragma unroll
    for (int d = 0; d < 8; ++d)
      KTu[d * KTSTR + base] = cvtpk(c0[d], c1[d]);

    int2 mv = *(const int2*)&mask[b * S_ + s];
    Mk[pi] = (mv.x ? 0xFFFFu : 0u) | (mv.y ? 0xFFFF0000u : 0u);
    okall &= (mv.x != 0) & (mv.y != 0);
  }
  int wall = __all(okall);
  if (lane == 0) sOK[wid] = wall;
  __syncthreads();
  const int allones = sOK[0] & sOK[1] & sOK[2] & sOK[3];

  uint4 cpat = {CONES_BITS, CONES_BITS, CONES_BITS, CONES_BITS};
  const f32x4 zf = {0.f, 0.f, 0.f, 0.f};
  const int vrow = (c & 7) * KTSTR;

#define KLOOP(MASKED)                                                         \
  _Pragma("unroll 2")                                                         \
  for (int kt = 0; kt < 64; ++kt) {                                           \
    float4 a0f = K4[kt * 32 + c];                                             \
    float4 a1f = K4[kt * 32 + 16 + c];                                        \
    uint4 vtu = *(const uint4*)&KTu[vrow + kt * 16 + 4 * g];                  \
    if (c == 8) vtu = cpat;                                                   \
    uint2 mA, mB;                                                             \
    if (MASKED) {                                                             \
      mA = *(const uint2*)&Mk[kt * 16 + 2 * g];                               \
      mB = *(const uint2*)&Mk[kt * 16 + 8 + 2 * g];                           \
    }                                                                         \
    short8 aK0 = __builtin_bit_cast(short8, a0f);                             \
    short8 aK1 = __builtin_bit_cast(short8, a1f);                             \
    short8 aV  = __builtin_bit_cast(short8, vtu);                             \
    _Pragma("unroll")                                                         \
    for (int qt = 0; qt < 4; ++qt) {                                          \
      f32x4 s0 = __builtin_amdgcn_mfma_f32_16x16x32_bf16(aK0, qf[qt], zf, 0, 0, 0); \
      f32x4 s1 = __builtin_amdgcn_mfma_f32_16x16x32_bf16(aK1, qf[qt], zf, 0, 0, 0); \
      unsigned w0 = cvtpk(ex2(s0[0]), ex2(s0[1]));                            \
      unsigned w1 = cvtpk(ex2(s0[2]), ex2(s0[3]));                            \
      unsigned w2 = cvtpk(ex2(s1[0]), ex2(s1[1]));                            \
      unsigned w3 = cvtpk(ex2(s1[2]), ex2(s1[3]));                            \
      if (MASKED) { w0 &= mA.x; w1 &= mA.y; w2 &= mB.x; w3 &= mB.y; }         \
      uint4 pu; pu.x = w0; pu.y = w1; pu.z = w2; pu.w = w3;                   \
      acc[qt] = __builtin_amdgcn_mfma_f32_16x16x32_bf16(                      \
          aV, __builtin_bit_cast(short8, pu), acc[qt], 0, 0, 0);              \
    }                                                                         \
  }

  if (allones) { KLOOP(0) } else { KLOOP(1) }
#undef KLOOP

  // ---- epilogue: acc rows 0..7 = numerator dims, row 8 = denominator*C ----
#pragma unroll
  for (int qt = 0; qt < 4; ++qt) {
    float den = __shfl(acc[qt][0], 32 + c);
    float rd = CORR_ / den;
    if (g < 2) {
      int qrow = qrow0 + qt * 16 + c;
      float4 o;
      o.x = acc[qt][0] * rd; o.y = acc[qt][1] * rd;
      o.z = acc[qt][2] * rd; o.w = acc[qt][3] * rd;
      *(float4*)&ao[((size_t)(b * S_ + qrow)) * E_ + h * DK_ + g * 4] = o;
    }
  }
}

// ---------------------------------------------------------------------------
// outproj2: C[m][n] = sum_f A[m][f]*W[n][f] + bias[n].  M=4096,N=256,K=256.
// BM=32, BN=64 -> grid 512 (2 blocks/CU). 256 thr, 2x4 micro-tile.
// ---------------------------------------------------------------------------
__global__ __launch_bounds__(256) void outproj2(
    const float* __restrict__ A, const float* __restrict__ W,
    const float* __restrict__ bias, float* __restrict__ C) {
  __shared__ float As[64][36];
  __shared__ float Ws[64][68];

  const int bm = blockIdx.x >> 2;       // 0..127
  const int bn = blockIdx.x & 3;        // 0..3
  const int tid = threadIdx.x;
  const int tm = tid >> 4, tn = tid & 15;
  const int m0 = tm * 2, n0 = tn * 4;

  float acc[2][4] = {};

  for (int kt = 0; kt < E_; kt += 64) {
#pragma unroll
    for (int f = 0; f < 2; ++f) {
      int fi = tid + f * 256;           // 0..511
      int row = fi >> 4;                // 0..31
      int kk = (fi & 15) << 2;
      float4 v = *(const float4*)&A[(size_t)(bm * 32 + row) * E_ + kt + kk];
      As[kk + 0][row] = v.x; As[kk + 1][row] = v.y;
      As[kk + 2][row] = v.z; As[kk + 3][row] = v.w;
    }
#pragma unroll
    for (int f = 0; f < 4; ++f) {
      int fi = tid + f * 256;           // 0..1023
      int row = fi >> 4;                // 0..63
      int kk = (fi & 15) << 2;
      float4 wv = *(const float4*)&W[(size_t)(bn * 64 + row) * E_ + kt + kk];
      Ws[kk + 0][row] = wv.x; Ws[kk + 1][row] = wv.y;
      Ws[kk + 2][row] = wv.z; Ws[kk + 3][row] = wv.w;
    }
    __syncthreads();

#pragma unroll 8
    for (int kk = 0; kk < 64; ++kk) {
      float2 a = *(const float2*)&As[kk][m0];
      float4 w = *(const float4*)&Ws[kk][n0];
      float ar[2] = {a.x, a.y};
      float wr[4] = {w.x, w.y, w.z, w.w};
#pragma unroll
      for (int i = 0; i < 2; ++i)
#pragma unroll
        for (int j = 0; j < 4; ++j)
          acc[i][j] = fmaf(ar[i], wr[j], acc[i][j]);
    }
    __syncthreads();
  }

  float4 bv = *(const float4*)&bias[bn * 64 + n0];
  float br[4] = {bv.x, bv.y, bv.z, bv.w};
#pragma unroll
  for (int i = 0; i < 2; ++i) {
    int m = bm * 32 + m0 + i;
    float4 outv = make_float4(acc[i][0] + br[0], acc[i][1] + br[1],
                              acc[i][2] + br[2], acc[i][3] + br[3]);
    *(float4*)&C[(size_t)m * E_ + bn * 64 + n0] = outv;
  }
}

// ---------------------------------------------------------------------------
extern "C" void kernel_launch(void* const* d_in, const int* in_sizes, int n_in,
                              void* d_out, int out_size, void* d_ws, size_t ws_size,
                              hipStream_t stream) {
  const float* x     = (const float*)d_in[0];
  const int*   mask  = (const int*)d_in[1];
  const float* theta = (const float*)d_in[2];
  const float* W     = (const float*)d_in[3];
  const float* bvec  = (const float*)d_in[4];
  float* out = (float*)d_out;

  float* ao = (float*)d_ws;   // [B][S][E] f32, 4MB

  attn5<<<B_ * H_ * 8, 256, 0, stream>>>(x, theta, mask, ao);
  outproj2<<<512, 256, 0, stream>>>(ao, W, bvec, out);
}

// Round 11
// 117.594 us; speedup vs baseline: 2.0552x; 1.0715x over previous
//
#include <hip/hip_runtime.h>

#define B_ 2
#define S_ 2048
#define E_ 256
#define H_ 32
#define DK_ 8
#define KTSTR 1036   // uint words per V'-row: 1024 + pad; conflict-free b128 reads

typedef float f32x4 __attribute__((ext_vector_type(4)));
typedef short short8 __attribute__((ext_vector_type(8)));

// scale folded into q: (q*SQ).(k*SQ) = (q.k) * log2(e)/sqrt(8)  -> exp2 arg
#define SQ_ 0.71419638f
// bf16(SQ) used for the ones-column of V'
#define CONES_F 0.71484375f
#define CONES_BITS 0x3F373F37u
#define CORR_ (CONES_F / SQ_)   // epilogue correction C/SQ

static __device__ __forceinline__ float ex2(float x) {
#if __has_builtin(__builtin_amdgcn_exp2f)
  return __builtin_amdgcn_exp2f(x);
#else
  float r; asm("v_exp_f32 %0, %1" : "=v"(r) : "v"(x)); return r;
#endif
}

static __device__ __forceinline__ unsigned cvtpk(float lo, float hi) {
  unsigned r;
  asm("v_cvt_pk_bf16_f32 %0, %1, %2" : "=v"(r) : "v"(lo), "v"(hi));
  return r;
}

// ---------------------------------------------------------------------------
// attn7: fused cos + MFMA attention, 8-wave blocks for trans-pipe feeding.
// Grid 512 = 64 bh x 8 q-chunks. Block 512 thr (8 waves); wave owns 32 q-rows
// (qt=2 x 16). LDS identical to R8's attn5 (69.6 KB -> 2 blocks/CU
// = 16 waves/CU = 4 waves/SIMD, vs R8's 2/SIMD).
// k-loop: 64 iters x 32 keys, zero barriers, zero cross-lane ops:
//   S^T = mfma(A=K, B=Q); P = exp2(S^T); cvt_pk -> B-frag DIRECTLY
//   (V'^T staged pi-permuted); ones-col (c==8 cpat) -> denominator.
// ---------------------------------------------------------------------------
__global__ __launch_bounds__(512) void attn7(
    const float* __restrict__ x, const float* __restrict__ theta,
    const int* __restrict__ mask, float* __restrict__ ao) {
  __shared__ float4 K4[S_];                 // 32 KB
  __shared__ unsigned KTu[DK_ * KTSTR];     // 33.2 KB
  __shared__ unsigned Mk[S_ / 2];           // 4 KB packed key-pair masks
  __shared__ int sOK[8];

  const int bh = blockIdx.x >> 3;
  const int qblk = (blockIdx.x & 7) * 256;
  const int b = bh >> 5, h = bh & 31;
  const int tid = threadIdx.x;              // 0..511
  const int wid = tid >> 6, lane = tid & 63;
  const int c = lane & 15, g = lane >> 4;

  const float* xb = x + (size_t)b * S_ * E_ + h * DK_;

  float th[8];
#pragma unroll
  for (int d = 0; d < 8; ++d) th[d] = theta[d];

  // ---- Q fragments (B operand): lanes >= 16 zero (k >= 8 padding) ----
  const int qrow0 = qblk + wid * 32;        // wave owns 32 rows
  short8 qf[2];
  f32x4 acc[2];
#pragma unroll
  for (int qt = 0; qt < 2; ++qt) {
    acc[qt] = (f32x4){0.f, 0.f, 0.f, 0.f};
    uint4 qq = {0u, 0u, 0u, 0u};
    if (lane < 16) {
      const float* xq = xb + (size_t)(qrow0 + qt * 16 + lane) * E_;
      float4 a = *(const float4*)xq;
      float4 bq = *(const float4*)(xq + 4);
      qq.x = cvtpk(__cosf(a.x + th[0]) * SQ_, __cosf(a.y + th[1]) * SQ_);
      qq.y = cvtpk(__cosf(a.z + th[2]) * SQ_, __cosf(a.w + th[3]) * SQ_);
      qq.z = cvtpk(__cosf(bq.x + th[4]) * SQ_, __cosf(bq.y + th[5]) * SQ_);
      qq.w = cvtpk(__cosf(bq.z + th[6]) * SQ_, __cosf(bq.w + th[7]) * SQ_);
    }
    qf[qt] = __builtin_bit_cast(short8, qq);
  }

  // ---- fused staging: cos + K4 (row-major) + KTu (pi-permuted) + masks ----
  // 1024 key-pairs, 512 threads -> 2 iterations: pi = it*512 + tid covers
  // [0,1024) exactly (coverage enumerated; R5-lesson check).
  int okall = 1;
#pragma unroll
  for (int it = 0; it < 2; ++it) {
    int pi = it * 512 + tid;            // key pair 0..1023
    int s = pi * 2;
    const float* xr = xb + (size_t)s * E_;
    float4 v00 = *(const float4*)xr;
    float4 v01 = *(const float4*)(xr + 4);
    float4 v10 = *(const float4*)(xr + E_);
    float4 v11 = *(const float4*)(xr + E_ + 4);
    float c0[8], c1[8];
    c0[0] = __cosf(v00.x + th[0]) * SQ_; c0[1] = __cosf(v00.y + th[1]) * SQ_;
    c0[2] = __cosf(v00.z + th[2]) * SQ_; c0[3] = __cosf(v00.w + th[3]) * SQ_;
    c0[4] = __cosf(v01.x + th[4]) * SQ_; c0[5] = __cosf(v01.y + th[5]) * SQ_;
    c0[6] = __cosf(v01.z + th[6]) * SQ_; c0[7] = __cosf(v01.w + th[7]) * SQ_;
    c1[0] = __cosf(v10.x + th[0]) * SQ_; c1[1] = __cosf(v10.y + th[1]) * SQ_;
    c1[2] = __cosf(v10.z + th[2]) * SQ_; c1[3] = __cosf(v10.w + th[3]) * SQ_;
    c1[4] = __cosf(v11.x + th[4]) * SQ_; c1[5] = __cosf(v11.y + th[5]) * SQ_;
    c1[6] = __cosf(v11.z + th[6]) * SQ_; c1[7] = __cosf(v11.w + th[7]) * SQ_;
    uint4 r0, r1;
    r0.x = cvtpk(c0[0], c0[1]); r0.y = cvtpk(c0[2], c0[3]);
    r0.z = cvtpk(c0[4], c0[5]); r0.w = cvtpk(c0[6], c0[7]);
    r1.x = cvtpk(c1[0], c1[1]); r1.y = cvtpk(c1[2], c1[3]);
    r1.z = cvtpk(c1[4], c1[5]); r1.w = cvtpk(c1[6], c1[7]);
    K4[s]     = __builtin_bit_cast(float4, r0);
    K4[s + 1] = __builtin_bit_cast(float4, r1);
    // pi-permuted word slot within the 16-word (32-key) kt group
    int ktg = pi >> 4, m = pi & 15;
    int w = 4 * ((m & 7) >> 1) + ((m >> 3) << 1) + (m & 1);
    int base = ktg * 16 + w;
#pragma unroll
    for (int d = 0; d < 8; ++d)
      KTu[d * KTSTR + base] = cvtpk(c0[d], c1[d]);

    int2 mv = *(const int2*)&mask[b * S_ + s];
    Mk[pi] = (mv.x ? 0xFFFFu : 0u) | (mv.y ? 0xFFFF0000u : 0u);
    okall &= (mv.x != 0) & (mv.y != 0);
  }
  int wall = __all(okall);
  if (lane == 0) sOK[wid] = wall;
  __syncthreads();
  const int allones = sOK[0] & sOK[1] & sOK[2] & sOK[3] &
                      sOK[4] & sOK[5] & sOK[6] & sOK[7];

  uint4 cpat = {CONES_BITS, CONES_BITS, CONES_BITS, CONES_BITS};
  const f32x4 zf = {0.f, 0.f, 0.f, 0.f};
  const int vrow = (c & 7) * KTSTR;

#define KLOOP(MASKED)                                                         \
  _Pragma("unroll 2")                                                         \
  for (int kt = 0; kt < 64; ++kt) {                                           \
    float4 a0f = K4[kt * 32 + c];                                             \
    float4 a1f = K4[kt * 32 + 16 + c];                                        \
    uint4 vtu = *(const uint4*)&KTu[vrow + kt * 16 + 4 * g];                  \
    if (c == 8) vtu = cpat;                                                   \
    uint2 mA, mB;                                                             \
    if (MASKED) {                                                             \
      mA = *(const uint2*)&Mk[kt * 16 + 2 * g];                               \
      mB = *(const uint2*)&Mk[kt * 16 + 8 + 2 * g];                           \
    }                                                                         \
    short8 aK0 = __builtin_bit_cast(short8, a0f);                             \
    short8 aK1 = __builtin_bit_cast(short8, a1f);                             \
    short8 aV  = __builtin_bit_cast(short8, vtu);                             \
    _Pragma("unroll")                                                         \
    for (int qt = 0; qt < 2; ++qt) {                                          \
      f32x4 s0 = __builtin_amdgcn_mfma_f32_16x16x32_bf16(aK0, qf[qt], zf, 0, 0, 0); \
      f32x4 s1 = __builtin_amdgcn_mfma_f32_16x16x32_bf16(aK1, qf[qt], zf, 0, 0, 0); \
      unsigned w0 = cvtpk(ex2(s0[0]), ex2(s0[1]));                            \
      unsigned w1 = cvtpk(ex2(s0[2]), ex2(s0[3]));                            \
      unsigned w2 = cvtpk(ex2(s1[0]), ex2(s1[1]));                            \
      unsigned w3 = cvtpk(ex2(s1[2]), ex2(s1[3]));                            \
      if (MASKED) { w0 &= mA.x; w1 &= mA.y; w2 &= mB.x; w3 &= mB.y; }         \
      uint4 pu; pu.x = w0; pu.y = w1; pu.z = w2; pu.w = w3;                   \
      acc[qt] = __builtin_amdgcn_mfma_f32_16x16x32_bf16(                      \
          aV, __builtin_bit_cast(short8, pu), acc[qt], 0, 0, 0);              \
    }                                                                         \
  }

  if (allones) { KLOOP(0) } else { KLOOP(1) }
#undef KLOOP

  // ---- epilogue: acc rows 0..7 = numerator dims, row 8 = denominator*C ----
#pragma unroll
  for (int qt = 0; qt < 2; ++qt) {
    float den = __shfl(acc[qt][0], 32 + c);
    float rd = CORR_ / den;
    if (g < 2) {
      int qrow = qrow0 + qt * 16 + c;
      float4 o;
      o.x = acc[qt][0] * rd; o.y = acc[qt][1] * rd;
      o.z = acc[qt][2] * rd; o.w = acc[qt][3] * rd;
      *(float4*)&ao[((size_t)(b * S_ + qrow)) * E_ + h * DK_ + g * 4] = o;
    }
  }
}

// ---------------------------------------------------------------------------
// outproj2: C[m][n] = sum_f A[m][f]*W[n][f] + bias[n].  M=4096,N=256,K=256.
// BM=32, BN=64 -> grid 512 (2 blocks/CU). 256 thr, 2x4 micro-tile.
// (unchanged from R8 passing version)
// ---------------------------------------------------------------------------
__global__ __launch_bounds__(256) void outproj2(
    const float* __restrict__ A, const float* __restrict__ W,
    const float* __restrict__ bias, float* __restrict__ C) {
  __shared__ float As[64][36];
  __shared__ float Ws[64][68];

  const int bm = blockIdx.x >> 2;       // 0..127
  const int bn = blockIdx.x & 3;        // 0..3
  const int tid = threadIdx.x;
  const int tm = tid >> 4, tn = tid & 15;
  const int m0 = tm * 2, n0 = tn * 4;

  float acc[2][4] = {};

  for (int kt = 0; kt < E_; kt += 64) {
#pragma unroll
    for (int f = 0; f < 2; ++f) {
      int fi = tid + f * 256;           // 0..511
      int row = fi >> 4;                // 0..31
      int kk = (fi & 15) << 2;
      float4 v = *(const float4*)&A[(size_t)(bm * 32 + row) * E_ + kt + kk];
      As[kk + 0][row] = v.x; As[kk + 1][row] = v.y;
      As[kk + 2][row] = v.z; As[kk + 3][row] = v.w;
    }
#pragma unroll
    for (int f = 0; f < 4; ++f) {
      int fi = tid + f * 256;           // 0..1023
      int row = fi >> 4;                // 0..63
      int kk = (fi & 15) << 2;
      float4 wv = *(const float4*)&W[(size_t)(bn * 64 + row) * E_ + kt + kk];
      Ws[kk + 0][row] = wv.x; Ws[kk + 1][row] = wv.y;
      Ws[kk + 2][row] = wv.z; Ws[kk + 3][row] = wv.w;
    }
    __syncthreads();

#pragma unroll 8
    for (int kk = 0; kk < 64; ++kk) {
      float2 a = *(const float2*)&As[kk][m0];
      float4 w = *(const float4*)&Ws[kk][n0];
      float ar[2] = {a.x, a.y};
      float wr[4] = {w.x, w.y, w.z, w.w};
#pragma unroll
      for (int i = 0; i < 2; ++i)
#pragma unroll
        for (int j = 0; j < 4; ++j)
          acc[i][j] = fmaf(ar[i], wr[j], acc[i][j]);
    }
    __syncthreads();
  }

  float4 bv = *(const float4*)&bias[bn * 64 + n0];
  float br[4] = {bv.x, bv.y, bv.z, bv.w};
#pragma unroll
  for (int i = 0; i < 2; ++i) {
    int m = bm * 32 + m0 + i;
    float4 outv = make_float4(acc[i][0] + br[0], acc[i][1] + br[1],
                              acc[i][2] + br[2], acc[i][3] + br[3]);
    *(float4*)&C[(size_t)m * E_ + bn * 64 + n0] = outv;
  }
}

// ---------------------------------------------------------------------------
extern "C" void kernel_launch(void* const* d_in, const int* in_sizes, int n_in,
                              void* d_out, int out_size, void* d_ws, size_t ws_size,
                              hipStream_t stream) {
  const float* x     = (const float*)d_in[0];
  const int*   mask  = (const int*)d_in[1];
  const float* theta = (const float*)d_in[2];
  const float* W     = (const float*)d_in[3];
  const float* bvec  = (const float*)d_in[4];
  float* out = (float*)d_out;

  float* ao = (float*)d_ws;   // [B][S][E] f32, 4MB

  attn7<<<B_ * H_ * 8, 512, 0, stream>>>(x, theta, mask, ao);
  outproj2<<<512, 256, 0, stream>>>(ao, W, bvec, out);
}